// Round 3
// baseline (5634.532 us; speedup 1.0000x reference)
//
#include <hip/hip_runtime.h>
#include <hip/hip_bf16.h>

#define DIMC 128
#define NHEAD 4
#define HEADD 32
#define WWIN 7
#define NWIN 49
#define IMGH 112
#define IMGW 112
#define NWX 16          // windows per spatial dim
#define SHIFT 3

// LDS layout (bytes):
//   region A (reused):
//     stage1: s_x   fp32 [49][132]                  = 25872
//     stage2: s_S   fp32 [49][57]  at offset 0      = 11172
//             s_o   bf16 [49][132] at offset 11264  = 12936  (ends 24200)
//   region B: s_qkv bf16 [49][390] at offset 25872  = 38220  (ends 64092)
#define SMEM_BYTES 64096
#define XSTRIDE 132
#define QKVSTRIDE 390
#define SSTRIDE 57
#define OSTRIDE 132
#define OFF_O 11264
#define OFF_QKV 25872

__global__ __launch_bounds__(256) void win_attn_fused(
    const float* __restrict__ x,
    const float* __restrict__ qkv_w,   // [384][128]
    const float* __restrict__ qkv_b,   // [384]
    const float* __restrict__ proj_w,  // [128][128]
    const float* __restrict__ proj_b,  // [128]
    const float* __restrict__ rpb,     // [169][4]
    float* __restrict__ out)
{
    __shared__ alignas(16) unsigned char smem[SMEM_BYTES];
    __shared__ int s_gpix[NWIN];
    __shared__ int s_reg[NWIN];

    float* s_x = (float*)smem;
    float* s_S = (float*)smem;
    __hip_bfloat16* s_o   = (__hip_bfloat16*)(smem + OFF_O);
    __hip_bfloat16* s_qkv = (__hip_bfloat16*)(smem + OFF_QKV);

    const int blk = blockIdx.x;
    const int b  = blk >> 8;        // /256 windows per image
    const int wi = blk & 255;
    const int wh = wi >> 4;
    const int ww = wi & 15;
    const int hs0 = wh * WWIN;
    const int ws0 = ww * WWIN;
    const int tid = threadIdx.x;

    // per-token metadata: global pixel (after reverse shift) + shift-mask region id
    if (tid < NWIN) {
        int r = tid / 7, c = tid - r * 7;
        int hs = hs0 + r, wsv = ws0 + c;
        int gh = hs + SHIFT; if (gh >= IMGH) gh -= IMGH;
        int gw = wsv + SHIFT; if (gw >= IMGW) gw -= IMGW;
        s_gpix[tid] = gh * IMGW + gw;
        int rh = (hs < IMGH - WWIN) ? 0 : ((hs < IMGH - SHIFT) ? 1 : 2);
        int rw = (wsv < IMGW - WWIN) ? 0 : ((wsv < IMGW - SHIFT) ? 1 : 2);
        s_reg[tid] = rh * 3 + rw;
    }

    // ---- stage 0: load x window (with cyclic shift) into LDS as fp32 ----
    const float* xb = x + (size_t)b * (IMGH * IMGW * DIMC);
    for (int idx = tid; idx < NWIN * 32; idx += 256) {     // float4 granules
        int i = idx >> 5;
        int c4 = idx & 31;
        int r = i / 7, c = i - r * 7;
        int gh = hs0 + r + SHIFT; if (gh >= IMGH) gh -= IMGH;
        int gw = ws0 + c + SHIFT; if (gw >= IMGW) gw -= IMGW;
        float4 v4 = *(const float4*)(xb + (((size_t)(gh * IMGW + gw)) << 7) + (c4 << 2));
        *(float4*)(s_x + i * XSTRIDE + (c4 << 2)) = v4;
    }
    __syncthreads();

    // ---- stage 1: qkv = xw @ qkv_w^T + b  -> bf16 in LDS ----
    for (int idx = tid; idx < NWIN * 384; idx += 256) {
        int i = idx / 384;
        int j = idx - i * 384;
        const float4* wrow = (const float4*)(qkv_w + (j << 7));
        const float4* xrow = (const float4*)(s_x + i * XSTRIDE);
        float acc = qkv_b[j];
        #pragma unroll 8
        for (int k4 = 0; k4 < 32; ++k4) {
            float4 w4 = wrow[k4];
            float4 x4 = xrow[k4];
            acc += w4.x * x4.x + w4.y * x4.y + w4.z * x4.z + w4.w * x4.w;
        }
        s_qkv[i * QKVSTRIDE + j] = __float2bfloat16(acc);
    }
    __syncthreads();

    const float scale = 0.17677669529663687f;   // 32^-0.5

    // ---- stage 2: per-head attention ----
    for (int h = 0; h < NHEAD; ++h) {
        const int qoff = h * HEADD;
        const int koff = DIMC + h * HEADD;
        const int voff = 2 * DIMC + h * HEADD;

        // S = scale * q k^T + bias + mask
        for (int idx = tid; idx < NWIN * NWIN; idx += 256) {
            int i = idx / 49;
            int j = idx - i * 49;
            const __hip_bfloat16* qrow = s_qkv + i * QKVSTRIDE + qoff;
            const __hip_bfloat16* krow = s_qkv + j * QKVSTRIDE + koff;
            float acc = 0.f;
            #pragma unroll 8
            for (int d = 0; d < HEADD; ++d)
                acc += __bfloat162float(qrow[d]) * __bfloat162float(krow[d]);
            int ri = i / 7, ci = i - ri * 7;
            int rj = j / 7, cj = j - rj * 7;
            int bidx = (ri - rj + 6) * 13 + (ci - cj + 6);
            float bias = rpb[bidx * NHEAD + h];
            float m = (s_reg[i] == s_reg[j]) ? 0.f : -100.f;
            s_S[i * SSTRIDE + j] = acc * scale + bias + m;
        }
        __syncthreads();

        // softmax per row (simple serial per-row; tiny work)
        if (tid < NWIN) {
            float* row = s_S + tid * SSTRIDE;
            float mx = -1e30f;
            #pragma unroll
            for (int j = 0; j < NWIN; ++j) mx = fmaxf(mx, row[j]);
            float sum = 0.f;
            #pragma unroll
            for (int j = 0; j < NWIN; ++j) { float e = __expf(row[j] - mx); row[j] = e; sum += e; }
            float inv = 1.f / sum;
            #pragma unroll
            for (int j = 0; j < NWIN; ++j) row[j] *= inv;
        }
        __syncthreads();

        // O_h = P @ v_h  -> bf16 into s_o columns [h*32, h*32+32)
        for (int idx = tid; idx < NWIN * HEADD; idx += 256) {
            int i = idx >> 5;
            int d = idx & 31;
            const __hip_bfloat16* vcol = s_qkv + voff + d;
            const float* srow = s_S + i * SSTRIDE;
            float acc = 0.f;
            #pragma unroll 7
            for (int j = 0; j < NWIN; ++j)
                acc += srow[j] * __bfloat162float(vcol[j * QKVSTRIDE]);
            s_o[i * OSTRIDE + qoff + d] = __float2bfloat16(acc);
        }
        __syncthreads();
    }

    // ---- stage 3: proj + scatter to output (with reverse shift) ----
    for (int idx = tid; idx < NWIN * DIMC; idx += 256) {
        int i = idx >> 7;
        int c = idx & 127;
        const float4* wrow = (const float4*)(proj_w + (c << 7));
        const __hip_bfloat16* orow = s_o + i * OSTRIDE;
        float acc = proj_b[c];
        #pragma unroll 8
        for (int k4 = 0; k4 < 32; ++k4) {
            float4 w4 = wrow[k4];
            acc += w4.x * __bfloat162float(orow[4 * k4 + 0])
                 + w4.y * __bfloat162float(orow[4 * k4 + 1])
                 + w4.z * __bfloat162float(orow[4 * k4 + 2])
                 + w4.w * __bfloat162float(orow[4 * k4 + 3]);
        }
        out[(((size_t)b * (IMGH * IMGW) + s_gpix[i]) << 7) + c] = acc;
    }
}

extern "C" void kernel_launch(void* const* d_in, const int* in_sizes, int n_in,
                              void* d_out, int out_size, void* d_ws, size_t ws_size,
                              hipStream_t stream) {
    const float* x      = (const float*)d_in[0];
    const float* qkv_w  = (const float*)d_in[1];
    const float* qkv_b  = (const float*)d_in[2];
    const float* proj_w = (const float*)d_in[3];
    const float* proj_b = (const float*)d_in[4];
    const float* rpb    = (const float*)d_in[5];
    float* out = (float*)d_out;

    hipLaunchKernelGGL(win_attn_fused, dim3(16 * NWX * NWX), dim3(256), 0, stream,
                       x, qkv_w, qkv_b, proj_w, proj_b, rpb, out);
}

// Round 5
// 200.968 us; speedup vs baseline: 28.0370x; 28.0370x over previous
//
#include <hip/hip_runtime.h>
#include <hip/hip_bf16.h>

typedef __attribute__((ext_vector_type(8))) short short8;
typedef __attribute__((ext_vector_type(4))) float floatx4;

#define IMGH 112
#define IMGW 112
#define SHIFT 3
#define NWIN 49

__device__ inline unsigned short f2bf(float f) {
    unsigned int u = __float_as_uint(f);
    unsigned int r = u + 0x7fffu + ((u >> 16) & 1u);
    return (unsigned short)(r >> 16);
}

__device__ inline floatx4 mfma16(short8 a, short8 b, floatx4 c) {
    return __builtin_amdgcn_mfma_f32_16x16x32_bf16(a, b, c, 0, 0, 0);
}

__device__ inline floatx4 zero4() {
    floatx4 z; z[0] = 0.f; z[1] = 0.f; z[2] = 0.f; z[3] = 0.f; return z;
}

__device__ inline short8 zero8() {
    short8 z; 
    #pragma unroll
    for (int i = 0; i < 8; ++i) z[i] = 0;
    return z;
}

// weight fp32 -> bf16 convert (runs once per launch, before main kernel)
__global__ __launch_bounds__(256) void convert_w(const float* __restrict__ qkv_w,
                                                 const float* __restrict__ proj_w,
                                                 short* __restrict__ ws) {
    int i = blockIdx.x * 256 + threadIdx.x;
    if (i < 49152) ws[i] = f2bf(qkv_w[i]);
    if (i < 16384) ws[49152 + i] = f2bf(proj_w[i]);
}

// One block per 7x7 window. 4 waves. All GEMMs on bf16 MFMA 16x16x32.
// LDS: s_qk [64][264] (Q cols 0-127 scaled, K cols 128-255), s_vt [128][72] (V^T),
//      s_P [64][72]. O aliases s_qk (stride 136) after heads complete.
__global__ __launch_bounds__(256, 2) void win_attn_mfma(
    const float* __restrict__ x,
    const float* __restrict__ qkv_b,
    const float* __restrict__ proj_b,
    const float* __restrict__ rpb,
    const short* __restrict__ wq,    // bf16 qkv_w [384][128]
    const short* __restrict__ wp,    // bf16 proj_w [128][128]
    float* __restrict__ out)
{
    __shared__ alignas(16) short s_qk[64 * 264];
    __shared__ alignas(16) short s_vt[128 * 72];
    __shared__ alignas(16) short s_P [64 * 72];

    const int tid = threadIdx.x;
    const int w   = tid >> 6;          // wave id 0..3
    const int l   = tid & 63;
    const int l15 = l & 15;
    const int lg  = l >> 4;            // 0..3

    const int blk = blockIdx.x;
    const int b   = blk >> 8;
    const int wi  = blk & 255;
    const int hs0 = (wi >> 4) * 7;
    const int ws0 = (wi & 15) * 7;

    const float* xb = x + (size_t)b * (IMGH * IMGW * 128);

    // ---- stage 1a: A-fragments of x straight from global (cyclic shift applied) ----
    short8 afrag[4][4];                 // [m][kk]
    #pragma unroll
    for (int m = 0; m < 4; ++m) {
        int row = m * 16 + l15;
        int rr = (row * 9363) >> 16;    // row/7 for 0..63
        int cc = row - rr * 7;
        int gh = hs0 + rr + SHIFT; if (gh >= IMGH) gh -= IMGH;
        int gw = ws0 + cc + SHIFT; if (gw >= IMGW) gw -= IMGW;
        const float* px = xb + (((size_t)(gh * IMGW + gw)) << 7) + lg * 8;
        bool valid = row < NWIN;
        #pragma unroll
        for (int kk = 0; kk < 4; ++kk) {
            short8 f = zero8();
            if (valid) {
                float4 a  = *(const float4*)(px + kk * 32);
                float4 c4 = *(const float4*)(px + kk * 32 + 4);
                f[0] = (short)f2bf(a.x);  f[1] = (short)f2bf(a.y);
                f[2] = (short)f2bf(a.z);  f[3] = (short)f2bf(a.w);
                f[4] = (short)f2bf(c4.x); f[5] = (short)f2bf(c4.y);
                f[6] = (short)f2bf(c4.z); f[7] = (short)f2bf(c4.w);
            }
            afrag[m][kk] = f;
        }
    }

    // ---- stage 1b: qkv GEMM. wave w owns n-tiles [6w, 6w+6) of 24 ----
    const float scale = 0.17677669529663687f;
    for (int n = w * 6; n < w * 6 + 6; ++n) {
        int j0 = n << 4;
        const short* wb = wq + ((j0 + l15) << 7) + lg * 8;
        short8 bfr[4];
        #pragma unroll
        for (int kk = 0; kk < 4; ++kk) bfr[kk] = *(const short8*)(wb + kk * 32);
        floatx4 acc[4];
        #pragma unroll
        for (int m = 0; m < 4; ++m) acc[m] = zero4();
        #pragma unroll
        for (int kk = 0; kk < 4; ++kk)
            #pragma unroll
            for (int m = 0; m < 4; ++m)
                acc[m] = mfma16(afrag[m][kk], bfr[kk], acc[m]);
        float bias = qkv_b[j0 + l15];
        #pragma unroll
        for (int m = 0; m < 4; ++m)
            #pragma unroll
            for (int c = 0; c < 4; ++c) {
                int row = m * 16 + lg * 4 + c;
                float v = acc[m][c] + bias;
                if (j0 < 256) {
                    s_qk[row * 264 + j0 + l15] = (short)f2bf(j0 < 128 ? v * scale : v);
                } else {
                    s_vt[(j0 - 256 + l15) * 72 + row] = (short)f2bf(v);  // V transposed
                }
            }
    }
    __syncthreads();

    // ---- per-lane bias/mask precompute (same for all heads) ----
    int   bidx[4][4];      // [c][n]
    float maskadd[4][4];
    {
        #pragma unroll
        for (int c = 0; c < 4; ++c) {
            int row = w * 16 + lg * 4 + c;
            int rowc = row < 49 ? row : 48;
            int ri = (rowc * 9363) >> 16;
            int ci = rowc - ri * 7;
            int hh = hs0 + ri, wwv = ws0 + ci;
            int reg_r = (hh < 105 ? 0 : (hh < 109 ? 1 : 2)) * 3
                      + (wwv < 105 ? 0 : (wwv < 109 ? 1 : 2));
            #pragma unroll
            for (int n = 0; n < 4; ++n) {
                int j = n * 16 + l15;
                bool jv = j < 49;
                int jc = jv ? j : 48;
                int rj = (jc * 9363) >> 16;
                int cj = jc - rj * 7;
                int hj = hs0 + rj, wj = ws0 + cj;
                int reg_c = (hj < 105 ? 0 : (hj < 109 ? 1 : 2)) * 3
                          + (wj < 105 ? 0 : (wj < 109 ? 1 : 2));
                bidx[c][n] = (ri - rj + 6) * 13 + (ci - cj + 6);
                maskadd[c][n] = !jv ? -1e30f : (reg_r == reg_c ? 0.f : -100.f);
            }
        }
    }

    // ---- stage 2: heads (no barriers inside; wave w owns query rows 16w..16w+15) ----
    floatx4 accO[4][2];    // [h][vt] kept in registers across heads
    for (int h = 0; h < 4; ++h) {
        short8 qf = *(const short8*)&s_qk[(w * 16 + l15) * 264 + h * 32 + lg * 8];
        floatx4 accS[4];
        #pragma unroll
        for (int n = 0; n < 4; ++n) {
            short8 kf = *(const short8*)&s_qk[(n * 16 + l15) * 264 + 128 + h * 32 + lg * 8];
            accS[n] = mfma16(qf, kf, zero4());
        }
        // bias + mask
        float p[4][4];     // [n][c]
        #pragma unroll
        for (int n = 0; n < 4; ++n)
            #pragma unroll
            for (int c = 0; c < 4; ++c)
                p[n][c] = accS[n][c] + rpb[bidx[c][n] * 4 + h] + maskadd[c][n];
        // softmax per query row (row lives in 16 lanes x 4 n-regs)
        #pragma unroll
        for (int c = 0; c < 4; ++c) {
            float mx = fmaxf(fmaxf(p[0][c], p[1][c]), fmaxf(p[2][c], p[3][c]));
            #pragma unroll
            for (int msk = 1; msk <= 8; msk <<= 1) mx = fmaxf(mx, __shfl_xor(mx, msk, 64));
            float sm = 0.f;
            #pragma unroll
            for (int n = 0; n < 4; ++n) { p[n][c] = __expf(p[n][c] - mx); sm += p[n][c]; }
            #pragma unroll
            for (int msk = 1; msk <= 8; msk <<= 1) sm += __shfl_xor(sm, msk, 64);
            float inv = 1.f / sm;
            #pragma unroll
            for (int n = 0; n < 4; ++n) p[n][c] *= inv;
        }
        // P -> LDS (own rows only)
        #pragma unroll
        for (int n = 0; n < 4; ++n)
            #pragma unroll
            for (int c = 0; c < 4; ++c)
                s_P[(w * 16 + lg * 4 + c) * 72 + n * 16 + l15] = (short)f2bf(p[n][c]);
        // PV (same-wave LDS dependency; compiler inserts lgkmcnt)
        short8 pa[2];
        #pragma unroll
        for (int kt = 0; kt < 2; ++kt)
            pa[kt] = *(const short8*)&s_P[(w * 16 + l15) * 72 + kt * 32 + lg * 8];
        #pragma unroll
        for (int vt = 0; vt < 2; ++vt) accO[h][vt] = zero4();
        #pragma unroll
        for (int kt = 0; kt < 2; ++kt)
            #pragma unroll
            for (int vt = 0; vt < 2; ++vt) {
                short8 vf = *(const short8*)&s_vt[(h * 32 + vt * 16 + l15) * 72 + kt * 32 + lg * 8];
                accO[h][vt] = mfma16(pa[kt], vf, accO[h][vt]);
            }
    }
    __syncthreads();

    // ---- O -> LDS (alias over dead Q/K region), stride 136 ----
    short* s_o = s_qk;
    #pragma unroll
    for (int h = 0; h < 4; ++h)
        #pragma unroll
        for (int vt = 0; vt < 2; ++vt)
            #pragma unroll
            for (int c = 0; c < 4; ++c)
                s_o[(w * 16 + lg * 4 + c) * 136 + h * 32 + vt * 16 + l15] =
                    (short)f2bf(accO[h][vt][c]);
    __syncthreads();

    // ---- stage 3: proj + scatter (reverse shift) ----
    short8 of[4][4];
    #pragma unroll
    for (int m = 0; m < 4; ++m)
        #pragma unroll
        for (int kk = 0; kk < 4; ++kk)
            of[m][kk] = *(const short8*)&s_o[(m * 16 + l15) * 136 + kk * 32 + lg * 8];
    for (int n = w * 2; n < w * 2 + 2; ++n) {
        int j0 = n << 4;
        const short* wb = wp + ((j0 + l15) << 7) + lg * 8;
        short8 bfr[4];
        #pragma unroll
        for (int kk = 0; kk < 4; ++kk) bfr[kk] = *(const short8*)(wb + kk * 32);
        floatx4 acc[4];
        #pragma unroll
        for (int m = 0; m < 4; ++m) acc[m] = zero4();
        #pragma unroll
        for (int kk = 0; kk < 4; ++kk)
            #pragma unroll
            for (int m = 0; m < 4; ++m)
                acc[m] = mfma16(of[m][kk], bfr[kk], acc[m]);
        float bias = proj_b[j0 + l15];
        #pragma unroll
        for (int m = 0; m < 4; ++m)
            #pragma unroll
            for (int c = 0; c < 4; ++c) {
                int row = m * 16 + lg * 4 + c;
                if (row < NWIN) {
                    int rr = (row * 9363) >> 16;
                    int cc = row - rr * 7;
                    int gh = hs0 + rr + SHIFT; if (gh >= IMGH) gh -= IMGH;
                    int gw = ws0 + cc + SHIFT; if (gw >= IMGW) gw -= IMGW;
                    out[(((size_t)b * (IMGH * IMGW) + gh * IMGW + gw)) * 128 + j0 + l15] =
                        acc[m][c] + bias;
                }
            }
    }
}

extern "C" void kernel_launch(void* const* d_in, const int* in_sizes, int n_in,
                              void* d_out, int out_size, void* d_ws, size_t ws_size,
                              hipStream_t stream) {
    const float* x      = (const float*)d_in[0];
    const float* qkv_w  = (const float*)d_in[1];
    const float* qkv_b  = (const float*)d_in[2];
    const float* proj_w = (const float*)d_in[3];
    const float* proj_b = (const float*)d_in[4];
    const float* rpb    = (const float*)d_in[5];
    float* out = (float*)d_out;
    short* wbf = (short*)d_ws;   // [0,49152) qkv_w bf16, [49152,65536) proj_w bf16

    hipLaunchKernelGGL(convert_w, dim3(192), dim3(256), 0, stream, qkv_w, proj_w, wbf);
    hipLaunchKernelGGL(win_attn_mfma, dim3(4096), dim3(256), 0, stream,
                       x, qkv_b, proj_b, rpb, wbf, wbf + 49152, out);
}

// Round 7
// 159.063 us; speedup vs baseline: 35.4233x; 1.2634x over previous
//
#include <hip/hip_runtime.h>
#include <hip/hip_bf16.h>

typedef __attribute__((ext_vector_type(8))) short short8;
typedef __attribute__((ext_vector_type(4))) float floatx4;

#define IMGH 112
#define IMGW 112
#define SHIFT 3
#define NWIN 49

#define XSTR 136     // s_xp row stride (x / P / O share this buffer)
#define QKSTR 264    // s_qk row stride (Q cols 0-127, K cols 128-255)
#define VTSTR 72     // s_vt row stride (V^T [128 feat][64 tok])

__device__ inline unsigned short f2bf(float f) {
    unsigned int u = __float_as_uint(f);
    unsigned int r = u + 0x7fffu + ((u >> 16) & 1u);
    return (unsigned short)(r >> 16);
}

__device__ inline floatx4 mfma16(short8 a, short8 b, floatx4 c) {
    return __builtin_amdgcn_mfma_f32_16x16x32_bf16(a, b, c, 0, 0, 0);
}

__device__ inline floatx4 zero4() {
    floatx4 z; z[0] = 0.f; z[1] = 0.f; z[2] = 0.f; z[3] = 0.f; return z;
}

// weight fp32 -> bf16 convert (runs once per launch, before main kernel)
__global__ __launch_bounds__(256) void convert_w(const float* __restrict__ qkv_w,
                                                 const float* __restrict__ proj_w,
                                                 short* __restrict__ ws) {
    int i = blockIdx.x * 256 + threadIdx.x;
    if (i < 49152) ws[i] = f2bf(qkv_w[i]);
    if (i < 16384) ws[49152 + i] = f2bf(proj_w[i]);
}

// One block per 7x7 window. 8 waves. x staged once in LDS; P/O reuse the x buffer.
__global__ __launch_bounds__(512, 4) void win_attn_mfma8(
    const float* __restrict__ x,
    const float* __restrict__ qkv_b,
    const float* __restrict__ proj_b,
    const float* __restrict__ rpb,
    const short* __restrict__ wq,    // bf16 qkv_w [384][128]
    const short* __restrict__ wp,    // bf16 proj_w [128][128]
    float* __restrict__ out)
{
    __shared__ alignas(16) short s_xp[64 * XSTR];    // 17408 B: x, then P (2 head slots), then O
    __shared__ alignas(16) short s_qk[64 * QKSTR];   // 33792 B
    __shared__ alignas(16) short s_vt[128 * VTSTR];  // 18432 B   total 69632 B -> 2 blocks/CU

    const int tid = threadIdx.x;
    const int w    = tid >> 6;         // wave 0..7
    const int l    = tid & 63;
    const int l15  = l & 15;
    const int lg   = l >> 4;           // 0..3
    const int hgrp = w >> 2;           // head pair: 0 -> heads 0,1 ; 1 -> heads 2,3
    const int m_w  = w & 3;            // query row tile (16 rows)

    const int blk = blockIdx.x;
    const int b   = blk >> 8;
    const int wi  = blk & 255;
    const int hs0 = (wi >> 4) * 7;
    const int ws0 = (wi & 15) * 7;

    const float* xb = x + (size_t)b * (IMGH * IMGW * 128);
    const float scale = 0.17677669529663687f;

    // ---- stage 0: x (with cyclic shift) -> LDS bf16, converted exactly once ----
    {
        int row  = tid >> 3;           // 0..63
        int col0 = (tid & 7) << 4;     // 0,16,...,112
        short8 v0, v1;
        if (row < NWIN) {
            int rr = (row * 9363) >> 16;
            int cc = row - rr * 7;
            int gh = hs0 + rr + SHIFT; if (gh >= IMGH) gh -= IMGH;
            int gw = ws0 + cc + SHIFT; if (gw >= IMGW) gw -= IMGW;
            const float* px = xb + (((size_t)(gh * IMGW + gw)) << 7) + col0;
            float4 a = *(const float4*)(px + 0);
            float4 c4 = *(const float4*)(px + 4);
            float4 e = *(const float4*)(px + 8);
            float4 g = *(const float4*)(px + 12);
            v0[0] = (short)f2bf(a.x);  v0[1] = (short)f2bf(a.y);
            v0[2] = (short)f2bf(a.z);  v0[3] = (short)f2bf(a.w);
            v0[4] = (short)f2bf(c4.x); v0[5] = (short)f2bf(c4.y);
            v0[6] = (short)f2bf(c4.z); v0[7] = (short)f2bf(c4.w);
            v1[0] = (short)f2bf(e.x);  v1[1] = (short)f2bf(e.y);
            v1[2] = (short)f2bf(e.z);  v1[3] = (short)f2bf(e.w);
            v1[4] = (short)f2bf(g.x);  v1[5] = (short)f2bf(g.y);
            v1[6] = (short)f2bf(g.z);  v1[7] = (short)f2bf(g.w);
        } else {
            #pragma unroll
            for (int i = 0; i < 8; ++i) { v0[i] = 0; v1[i] = 0; }
        }
        *(short8*)&s_xp[row * XSTR + col0]     = v0;
        *(short8*)&s_xp[row * XSTR + col0 + 8] = v1;
    }
    __syncthreads();

    // ---- stage 1: qkv GEMM. wave w owns n-tiles [3w, 3w+3) of 24 ----
    {
        short8 bfr[3][4];
        #pragma unroll
        for (int i = 0; i < 3; ++i) {
            int j0 = (w * 3 + i) << 4;
            const short* wb = wq + ((j0 + l15) << 7) + lg * 8;
            #pragma unroll
            for (int kk = 0; kk < 4; ++kk) bfr[i][kk] = *(const short8*)(wb + kk * 32);
        }
        float biasr[3];
        #pragma unroll
        for (int i = 0; i < 3; ++i) biasr[i] = qkv_b[((w * 3 + i) << 4) + l15];

        for (int m = 0; m < 4; ++m) {
            short8 af[4];
            #pragma unroll
            for (int kk = 0; kk < 4; ++kk)
                af[kk] = *(const short8*)&s_xp[(m * 16 + l15) * XSTR + kk * 32 + lg * 8];
            floatx4 acc[3];
            #pragma unroll
            for (int i = 0; i < 3; ++i) acc[i] = zero4();
            #pragma unroll
            for (int kk = 0; kk < 4; ++kk)
                #pragma unroll
                for (int i = 0; i < 3; ++i)
                    acc[i] = mfma16(af[kk], bfr[i][kk], acc[i]);
            #pragma unroll
            for (int i = 0; i < 3; ++i) {
                int j0 = (w * 3 + i) << 4;
                #pragma unroll
                for (int c = 0; c < 4; ++c) {
                    int row = m * 16 + lg * 4 + c;
                    float v = acc[i][c] + biasr[i];
                    if (j0 < 128)      s_qk[row * QKSTR + j0 + l15] = (short)f2bf(v * scale);
                    else if (j0 < 256) s_qk[row * QKSTR + j0 + l15] = (short)f2bf(v);
                    else               s_vt[(j0 - 256 + l15) * VTSTR + row] = (short)f2bf(v);
                }
            }
        }
    }
    __syncthreads();   // x fully consumed; s_xp becomes P storage

    // ---- per-lane bias/mask precompute (rows m_w*16+lg*4+c, keys n*16+l15) ----
    int   bidx[4][4];      // [c][n]
    float maskadd[4][4];
    {
        #pragma unroll
        for (int c = 0; c < 4; ++c) {
            int row = m_w * 16 + lg * 4 + c;
            int rowc = row < 49 ? row : 48;
            int ri = (rowc * 9363) >> 16;
            int ci = rowc - ri * 7;
            int hh = hs0 + ri, wwv = ws0 + ci;
            int reg_r = (hh < 105 ? 0 : (hh < 109 ? 1 : 2)) * 3
                      + (wwv < 105 ? 0 : (wwv < 109 ? 1 : 2));
            #pragma unroll
            for (int n = 0; n < 4; ++n) {
                int j = n * 16 + l15;
                bool jv = j < 49;
                int jc = jv ? j : 48;
                int rj = (jc * 9363) >> 16;
                int cj = jc - rj * 7;
                int hj = hs0 + rj, wj = ws0 + cj;
                int reg_c = (hj < 105 ? 0 : (hj < 109 ? 1 : 2)) * 3
                          + (wj < 105 ? 0 : (wj < 109 ? 1 : 2));
                bidx[c][n] = (ri - rj + 6) * 13 + (ci - cj + 6);
                maskadd[c][n] = !jv ? -1e30f : (reg_r == reg_c ? 0.f : -100.f);
            }
        }
    }

    // ---- stage 2: wave handles 2 heads (hgrp*2+hh) for its 16 query rows ----
    floatx4 accO[2][2];    // [hh][vt]
    for (int hh = 0; hh < 2; ++hh) {
        const int h = hgrp * 2 + hh;
        short8 qf = *(const short8*)&s_qk[(m_w * 16 + l15) * QKSTR + h * 32 + lg * 8];
        floatx4 accS[4];
        #pragma unroll
        for (int n = 0; n < 4; ++n) {
            short8 kf = *(const short8*)&s_qk[(n * 16 + l15) * QKSTR + 128 + h * 32 + lg * 8];
            accS[n] = mfma16(qf, kf, zero4());
        }
        float p[4][4];     // [n][c]
        #pragma unroll
        for (int n = 0; n < 4; ++n)
            #pragma unroll
            for (int c = 0; c < 4; ++c)
                p[n][c] = accS[n][c] + rpb[bidx[c][n] * 4 + h] + maskadd[c][n];
        // softmax per query row (64 keys spread over 4 n-regs x 16 lanes)
        #pragma unroll
        for (int c = 0; c < 4; ++c) {
            float mx = fmaxf(fmaxf(p[0][c], p[1][c]), fmaxf(p[2][c], p[3][c]));
            #pragma unroll
            for (int msk = 1; msk <= 8; msk <<= 1) mx = fmaxf(mx, __shfl_xor(mx, msk, 64));
            float sm = 0.f;
            #pragma unroll
            for (int n = 0; n < 4; ++n) { p[n][c] = __expf(p[n][c] - mx); sm += p[n][c]; }
            #pragma unroll
            for (int msk = 1; msk <= 8; msk <<= 1) sm += __shfl_xor(sm, msk, 64);
            float inv = 1.f / sm;
            #pragma unroll
            for (int n = 0; n < 4; ++n) p[n][c] *= inv;
        }
        // P -> s_xp (head slot hh at col 0 / 72; rows are wave-private)
        #pragma unroll
        for (int n = 0; n < 4; ++n)
            #pragma unroll
            for (int c = 0; c < 4; ++c)
                s_xp[(m_w * 16 + lg * 4 + c) * XSTR + hh * 72 + n * 16 + l15] = (short)f2bf(p[n][c]);
        short8 pa[2];
        #pragma unroll
        for (int kt = 0; kt < 2; ++kt)
            pa[kt] = *(const short8*)&s_xp[(m_w * 16 + l15) * XSTR + hh * 72 + kt * 32 + lg * 8];
        #pragma unroll
        for (int vt = 0; vt < 2; ++vt) accO[hh][vt] = zero4();
        #pragma unroll
        for (int kt = 0; kt < 2; ++kt)
            #pragma unroll
            for (int vt = 0; vt < 2; ++vt) {
                short8 vf = *(const short8*)&s_vt[(h * 32 + vt * 16 + l15) * VTSTR + kt * 32 + lg * 8];
                accO[hh][vt] = mfma16(pa[kt], vf, accO[hh][vt]);
            }
    }
    __syncthreads();   // all P consumed before O overwrites s_xp

    // ---- O -> s_xp [64][XSTR] (cols hgrp*64 + hh*32 + vt*16 + l15) ----
    #pragma unroll
    for (int hh = 0; hh < 2; ++hh)
        #pragma unroll
        for (int vt = 0; vt < 2; ++vt)
            #pragma unroll
            for (int c = 0; c < 4; ++c)
                s_xp[(m_w * 16 + lg * 4 + c) * XSTR + hgrp * 64 + hh * 32 + vt * 16 + l15] =
                    (short)f2bf(accO[hh][vt][c]);
    __syncthreads();

    // ---- stage 3: proj + scatter. wave w owns output n-tile j0 = 16w ----
    {
        floatx4 acc[4];
        #pragma unroll
        for (int m = 0; m < 4; ++m) acc[m] = zero4();
        const short* wb = wp + ((w * 16 + l15) << 7) + lg * 8;
        #pragma unroll
        for (int kk = 0; kk < 4; ++kk) {
            short8 bfr = *(const short8*)(wb + kk * 32);
            #pragma unroll
            for (int m = 0; m < 4; ++m) {
                short8 of = *(const short8*)&s_xp[(m * 16 + l15) * XSTR + kk * 32 + lg * 8];
                acc[m] = mfma16(of, bfr, acc[m]);
            }
        }
        float bias = proj_b[w * 16 + l15];
        #pragma unroll
        for (int m = 0; m < 4; ++m)
            #pragma unroll
            for (int c = 0; c < 4; ++c) {
                int row = m * 16 + lg * 4 + c;
                if (row < NWIN) {
                    int rr = (row * 9363) >> 16;
                    int cc = row - rr * 7;
                    int gh = hs0 + rr + SHIFT; if (gh >= IMGH) gh -= IMGH;
                    int gw = ws0 + cc + SHIFT; if (gw >= IMGW) gw -= IMGW;
                    out[(((size_t)b * (IMGH * IMGW) + gh * IMGW + gw)) * 128 + w * 16 + l15] =
                        acc[m][c] + bias;
                }
            }
    }
}

extern "C" void kernel_launch(void* const* d_in, const int* in_sizes, int n_in,
                              void* d_out, int out_size, void* d_ws, size_t ws_size,
                              hipStream_t stream) {
    const float* x      = (const float*)d_in[0];
    const float* qkv_w  = (const float*)d_in[1];
    const float* qkv_b  = (const float*)d_in[2];
    const float* proj_w = (const float*)d_in[3];
    const float* proj_b = (const float*)d_in[4];
    const float* rpb    = (const float*)d_in[5];
    float* out = (float*)d_out;
    short* wbf = (short*)d_ws;   // [0,49152) qkv_w bf16, [49152,65536) proj_w bf16

    hipLaunchKernelGGL(convert_w, dim3(192), dim3(256), 0, stream, qkv_w, proj_w, wbf);
    hipLaunchKernelGGL(win_attn_mfma8, dim3(4096), dim3(512), 0, stream,
                       x, qkv_b, proj_b, rpb, wbf, wbf + 49152, out);
}

// Round 9
// 126.505 us; speedup vs baseline: 44.5402x; 1.2574x over previous
//
#include <hip/hip_runtime.h>
#include <hip/hip_bf16.h>

typedef __attribute__((ext_vector_type(8))) short short8;
typedef __attribute__((ext_vector_type(4))) float floatx4;

#define IMGH 112
#define IMGW 112
#define SHIFT 3
#define NWIN 49

#define XSTR 152     // s_xp row stride (x / P / O); 304B = 19*16, 76dw = 12 mod 32
#define QKSTR 280    // s_qk row stride (Q 0-127, K 128-255); 560B, 140dw = 12 mod 32
#define VTSTR 88     // s_vt row stride; 176B, 44dw = 12 mod 32

#define LOG2E 1.4426950408889634f
#define QSCALE (0.17677669529663687f * LOG2E)
#define NMASK (-100.0f * LOG2E)

__device__ inline unsigned short f2bf1(float f) {
    unsigned r;
    asm("v_cvt_pk_bf16_f32 %0, %1, %1" : "=v"(r) : "v"(f));
    return (unsigned short)r;
}
__device__ inline unsigned cvtpk(float lo, float hi) {
    unsigned r;
    asm("v_cvt_pk_bf16_f32 %0, %1, %2" : "=v"(r) : "v"(lo), "v"(hi));
    return r;
}

__device__ inline floatx4 mfma16(short8 a, short8 b, floatx4 c) {
    return __builtin_amdgcn_mfma_f32_16x16x32_bf16(a, b, c, 0, 0, 0);
}
__device__ inline floatx4 zero4() {
    floatx4 z; z[0] = 0.f; z[1] = 0.f; z[2] = 0.f; z[3] = 0.f; return z;
}

// weight fp32 -> bf16 (Q rows pre-scaled by scale*log2e)
__global__ __launch_bounds__(256) void convert_w(const float* __restrict__ qkv_w,
                                                 const float* __restrict__ proj_w,
                                                 short* __restrict__ ws) {
    int i = blockIdx.x * 256 + threadIdx.x;
    if (i < 49152) {
        float v = qkv_w[i];
        if (i < 16384) v *= QSCALE;          // rows 0..127 = Q features
        ws[i] = (short)f2bf1(v);
    }
    if (i < 16384) ws[49152 + i] = (short)f2bf1(proj_w[i]);
}

// One block per 7x7 window, 8 waves. All GEMMs bf16 MFMA; softmax in exp2 domain.
__global__ __launch_bounds__(512, 4) void win_attn_mfma8(
    const float* __restrict__ x,
    const float* __restrict__ qkv_b,
    const float* __restrict__ proj_b,
    const float* __restrict__ rpb,
    const short* __restrict__ wq,    // bf16 qkv_w [384][128] (Q rows scaled)
    const short* __restrict__ wp,    // bf16 proj_w [128][128]
    float* __restrict__ out)
{
    __shared__ alignas(16) short s_xp[64 * XSTR];    // 19456 B: x -> P slots -> O
    __shared__ alignas(16) short s_qk[64 * QKSTR];   // 35840 B
    __shared__ alignas(16) short s_vt[128 * VTSTR];  // 22528 B
    __shared__ float2 s_rpb[2][169];                 // 2704 B, pre-scaled by LOG2E
    __shared__ int s_meta[64];                       // t13 | reg<<8

    const int tid = threadIdx.x;
    const int w    = tid >> 6;         // wave 0..7
    const int l    = tid & 63;
    const int l15  = l & 15;
    const int lg   = l >> 4;           // 0..3
    const int hgrp = w >> 2;           // head pair 0/1
    const int m_w  = w & 3;            // query row tile

    const int blk = blockIdx.x;
    const int b   = blk >> 8;
    const int wi  = blk & 255;
    const int hs0 = (wi >> 4) * 7;
    const int ws0 = (wi & 15) * 7;

    const float* xb = x + (size_t)b * (IMGH * IMGW * 128);

    // ---- stage 0: metadata + rpb + x -> LDS ----
    if (tid < 64) {
        int rowc = tid < NWIN ? tid : NWIN - 1;
        int ri = (rowc * 9363) >> 16;
        int ci = rowc - ri * 7;
        int hc = hs0 + ri, wc = ws0 + ci;
        int reg = (hc < 105 ? 0 : (hc < 109 ? 1 : 2)) * 3
                + (wc < 105 ? 0 : (wc < 109 ? 1 : 2));
        if (tid >= NWIN) reg = 255;
        s_meta[tid] = (ri * 13 + ci) | (reg << 8);
    }
    if (tid < 338) {
        int hg  = tid < 169 ? 0 : 1;
        int idx = tid - hg * 169;
        float2 v = *(const float2*)(rpb + idx * 4 + hg * 2);
        v.x *= LOG2E; v.y *= LOG2E;
        s_rpb[hg][idx] = v;
    }
    {
        int row  = tid >> 3;           // 0..63
        int col0 = (tid & 7) << 4;     // 0,16,...,112
        uint4 u0 = {0,0,0,0}, u1 = {0,0,0,0};
        if (row < NWIN) {
            int rr = (row * 9363) >> 16;
            int cc = row - rr * 7;
            int gh = hs0 + rr + SHIFT; if (gh >= IMGH) gh -= IMGH;
            int gw = ws0 + cc + SHIFT; if (gw >= IMGW) gw -= IMGW;
            const float* px = xb + (((size_t)(gh * IMGW + gw)) << 7) + col0;
            float4 a = *(const float4*)(px + 0);
            float4 c4 = *(const float4*)(px + 4);
            float4 e = *(const float4*)(px + 8);
            float4 g = *(const float4*)(px + 12);
            u0.x = cvtpk(a.x, a.y);   u0.y = cvtpk(a.z, a.w);
            u0.z = cvtpk(c4.x, c4.y); u0.w = cvtpk(c4.z, c4.w);
            u1.x = cvtpk(e.x, e.y);   u1.y = cvtpk(e.z, e.w);
            u1.z = cvtpk(g.x, g.y);   u1.w = cvtpk(g.z, g.w);
        }
        *(uint4*)&s_xp[row * XSTR + col0]     = u0;
        *(uint4*)&s_xp[row * XSTR + col0 + 8] = u1;
    }
    __syncthreads();

    // ---- stage 1: qkv GEMM. wave w owns n-tiles [3w, 3w+3) of 24 ----
    {
        short8 bfr[3][4];
        float  biasr[3];
        #pragma unroll
        for (int i = 0; i < 3; ++i) {
            int j0 = (w * 3 + i) << 4;
            const short* wb = wq + ((j0 + l15) << 7) + lg * 8;
            #pragma unroll
            for (int kk = 0; kk < 4; ++kk) bfr[i][kk] = *(const short8*)(wb + kk * 32);
            float bb = qkv_b[j0 + l15];
            biasr[i] = (j0 < 128) ? bb * QSCALE : bb;
        }
        for (int m = 0; m < 4; ++m) {
            short8 af[4];
            #pragma unroll
            for (int kk = 0; kk < 4; ++kk)
                af[kk] = *(const short8*)&s_xp[(m * 16 + l15) * XSTR + kk * 32 + lg * 8];
            floatx4 acc[3];
            #pragma unroll
            for (int i = 0; i < 3; ++i) acc[i] = zero4();
            #pragma unroll
            for (int kk = 0; kk < 4; ++kk)
                #pragma unroll
                for (int i = 0; i < 3; ++i)
                    acc[i] = mfma16(af[kk], bfr[i][kk], acc[i]);
            #pragma unroll
            for (int i = 0; i < 3; ++i) {
                int j0 = (w * 3 + i) << 4;
                #pragma unroll
                for (int c = 0; c < 4; ++c) {
                    int row = m * 16 + lg * 4 + c;
                    unsigned short v = f2bf1(acc[i][c] + biasr[i]);
                    if (j0 < 256) s_qk[row * QKSTR + j0 + l15] = (short)v;
                    else          s_vt[(j0 - 256 + l15) * VTSTR + row] = (short)v;
                }
            }
        }
    }
    __syncthreads();   // x consumed; s_xp becomes P/O storage

    // ---- bias+mask for both heads of this wave's pair, computed once ----
    float2 b2[4][4];   // [c][n]
    {
        int mj[4];
        #pragma unroll
        for (int n = 0; n < 4; ++n) mj[n] = s_meta[n * 16 + l15];
        #pragma unroll
        for (int c = 0; c < 4; ++c) {
            int mi = s_meta[m_w * 16 + lg * 4 + c];
            int ti = mi & 255, gi = mi >> 8;
            #pragma unroll
            for (int n = 0; n < 4; ++n) {
                int d = ti - (mj[n] & 255) + 84;
                float msk = (gi == (mj[n] >> 8)) ? 0.f : NMASK;
                float2 r2 = s_rpb[hgrp][d];
                b2[c][n].x = r2.x + msk;
                b2[c][n].y = r2.y + msk;
            }
        }
    }

    // ---- stage 2: two heads per wave; P slot keyed on hgrp (race-free),
    //      reused serially across hh (intra-wave LDS ordering) ----
    floatx4 accO[2][2];    // [hh][vt]
    float   inv[2][4];     // [hh][c]
    #pragma unroll
    for (int hh = 0; hh < 2; ++hh) {
        const int h = hgrp * 2 + hh;
        short8 qf = *(const short8*)&s_qk[(m_w * 16 + l15) * QKSTR + h * 32 + lg * 8];
        floatx4 accS[4];
        #pragma unroll
        for (int n = 0; n < 4; ++n) {
            short8 kf = *(const short8*)&s_qk[(n * 16 + l15) * QKSTR + 128 + h * 32 + lg * 8];
            accS[n] = mfma16(qf, kf, zero4());
        }
        float p[4][4];     // [n][c]
        #pragma unroll
        for (int n = 0; n < 4; ++n)
            #pragma unroll
            for (int c = 0; c < 4; ++c)
                p[n][c] = accS[n][c] + (hh ? b2[c][n].y : b2[c][n].x);
        // softmax (exp2 domain), normalization deferred to O-write
        #pragma unroll
        for (int c = 0; c < 4; ++c) {
            float mx = fmaxf(fmaxf(p[0][c], p[1][c]), fmaxf(p[2][c], p[3][c]));
            #pragma unroll
            for (int msk = 1; msk <= 8; msk <<= 1) mx = fmaxf(mx, __shfl_xor(mx, msk, 64));
            float sm = 0.f;
            #pragma unroll
            for (int n = 0; n < 4; ++n) { p[n][c] = exp2f(p[n][c] - mx); sm += p[n][c]; }
            #pragma unroll
            for (int msk = 1; msk <= 8; msk <<= 1) sm += __shfl_xor(sm, msk, 64);
            inv[hh][c] = 1.f / sm;
        }
        // P -> s_xp slot (cols hgrp*72.., rows m_w*16.. : wave-private)
        #pragma unroll
        for (int n = 0; n < 4; ++n)
            #pragma unroll
            for (int c = 0; c < 4; ++c)
                s_xp[(m_w * 16 + lg * 4 + c) * XSTR + hgrp * 72 + n * 16 + l15] =
                    (short)f2bf1(p[n][c]);
        short8 pa[2];
        #pragma unroll
        for (int kt = 0; kt < 2; ++kt)
            pa[kt] = *(const short8*)&s_xp[(m_w * 16 + l15) * XSTR + hgrp * 72 + kt * 32 + lg * 8];
        #pragma unroll
        for (int vt = 0; vt < 2; ++vt) accO[hh][vt] = zero4();
        #pragma unroll
        for (int kt = 0; kt < 2; ++kt)
            #pragma unroll
            for (int vt = 0; vt < 2; ++vt) {
                short8 vf = *(const short8*)&s_vt[(h * 32 + vt * 16 + l15) * VTSTR + kt * 32 + lg * 8];
                accO[hh][vt] = mfma16(pa[kt], vf, accO[hh][vt]);
            }
    }
    __syncthreads();   // all P consumed before O overwrites s_xp

    // ---- O (normalized here) -> s_xp cols hgrp*64+hh*32+vt*16+l15 ----
    #pragma unroll
    for (int hh = 0; hh < 2; ++hh)
        #pragma unroll
        for (int vt = 0; vt < 2; ++vt)
            #pragma unroll
            for (int c = 0; c < 4; ++c)
                s_xp[(m_w * 16 + lg * 4 + c) * XSTR + hgrp * 64 + hh * 32 + vt * 16 + l15] =
                    (short)f2bf1(accO[hh][vt][c] * inv[hh][c]);
    __syncthreads();

    // ---- stage 3: proj + scatter (reverse shift). wave w owns n-tile 16w ----
    {
        floatx4 acc[4];
        #pragma unroll
        for (int m = 0; m < 4; ++m) acc[m] = zero4();
        const short* wb = wp + ((w * 16 + l15) << 7) + lg * 8;
        #pragma unroll
        for (int kk = 0; kk < 4; ++kk) {
            short8 bfr = *(const short8*)(wb + kk * 32);
            #pragma unroll
            for (int m = 0; m < 4; ++m) {
                short8 of = *(const short8*)&s_xp[(m * 16 + l15) * XSTR + kk * 32 + lg * 8];
                acc[m] = mfma16(of, bfr, acc[m]);
            }
        }
        float bias = proj_b[w * 16 + l15];
        #pragma unroll
        for (int m = 0; m < 4; ++m)
            #pragma unroll
            for (int c = 0; c < 4; ++c) {
                int row = m * 16 + lg * 4 + c;
                if (row < NWIN) {
                    int rr = (row * 9363) >> 16;
                    int cc = row - rr * 7;
                    int gh = hs0 + rr + SHIFT; if (gh >= IMGH) gh -= IMGH;
                    int gw = ws0 + cc + SHIFT; if (gw >= IMGW) gw -= IMGW;
                    out[(((size_t)b * (IMGH * IMGW) + gh * IMGW + gw)) * 128 + w * 16 + l15] =
                        acc[m][c] + bias;
                }
            }
    }
}

extern "C" void kernel_launch(void* const* d_in, const int* in_sizes, int n_in,
                              void* d_out, int out_size, void* d_ws, size_t ws_size,
                              hipStream_t stream) {
    const float* x      = (const float*)d_in[0];
    const float* qkv_w  = (const float*)d_in[1];
    const float* qkv_b  = (const float*)d_in[2];
    const float* proj_w = (const float*)d_in[3];
    const float* proj_b = (const float*)d_in[4];
    const float* rpb    = (const float*)d_in[5];
    float* out = (float*)d_out;
    short* wbf = (short*)d_ws;   // [0,49152) qkv_w bf16 (Q rows pre-scaled), [49152,65536) proj_w

    hipLaunchKernelGGL(convert_w, dim3(192), dim3(256), 0, stream, qkv_w, proj_w, wbf);
    hipLaunchKernelGGL(win_attn_mfma8, dim3(4096), dim3(512), 0, stream,
                       x, qkv_b, proj_b, rpb, wbf, wbf + 49152, out);
}

// Round 13
// 121.047 us; speedup vs baseline: 46.5483x; 1.0451x over previous
//
#include <hip/hip_runtime.h>
#include <hip/hip_bf16.h>

typedef __attribute__((ext_vector_type(8))) short short8;
typedef __attribute__((ext_vector_type(4))) float floatx4;

#define IMGH 112
#define IMGW 112
#define SHIFT 3
#define NWIN 49

#define XSTR 152     // s_xp row stride (x / P / O)
#define QKSTR 280    // s_qk row stride (Q 0-127, K 128-255)
#define VTSTR 88     // s_vt row stride (V^T)

#define LOG2E 1.4426950408889634f
#define QSCALE (0.17677669529663687f * LOG2E)
#define NMASK (-100.0f * LOG2E)

__device__ inline unsigned short f2bf1(float f) {
    unsigned r;
    asm("v_cvt_pk_bf16_f32 %0, %1, %1" : "=v"(r) : "v"(f));
    return (unsigned short)r;
}
__device__ inline unsigned cvtpk(float lo, float hi) {
    unsigned r;
    asm("v_cvt_pk_bf16_f32 %0, %1, %2" : "=v"(r) : "v"(lo), "v"(hi));
    return r;
}

__device__ inline floatx4 mfma16(short8 a, short8 b, floatx4 c) {
    return __builtin_amdgcn_mfma_f32_16x16x32_bf16(a, b, c, 0, 0, 0);
}
__device__ inline floatx4 zero4() {
    floatx4 z; z[0] = 0.f; z[1] = 0.f; z[2] = 0.f; z[3] = 0.f; return z;
}

// weight fp32 -> bf16 (Q rows pre-scaled by scale*log2e)
__global__ __launch_bounds__(256) void convert_w(const float* __restrict__ qkv_w,
                                                 const float* __restrict__ proj_w,
                                                 short* __restrict__ ws) {
    int i = blockIdx.x * 256 + threadIdx.x;
    if (i < 49152) {
        float v = qkv_w[i];
        if (i < 16384) v *= QSCALE;          // rows 0..127 = Q features
        ws[i] = (short)f2bf1(v);
    }
    if (i < 16384) ws[49152 + i] = (short)f2bf1(proj_w[i]);
}

// One block per 7x7 window, 8 waves. EXACT round-9 structure + s_gout only.
__global__ __launch_bounds__(512, 4) void win_attn_mfma8(
    const float* __restrict__ x,
    const float* __restrict__ qkv_b,
    const float* __restrict__ proj_b,
    const float* __restrict__ rpb,
    const short* __restrict__ wq,    // bf16 qkv_w [384][128] (Q rows scaled)
    const short* __restrict__ wp,    // bf16 proj_w [128][128]
    float* __restrict__ out)
{
    __shared__ alignas(16) short s_xp[64 * XSTR];    // x -> P slots -> O
    __shared__ alignas(16) short s_qk[64 * QKSTR];
    __shared__ alignas(16) short s_vt[128 * VTSTR];
    __shared__ float2 s_rpb[2][169];                 // pre-scaled by LOG2E
    __shared__ int s_meta[64];                       // t13 | reg<<8
    __shared__ int s_gout[64];                       // scatter pixel index

    const int tid = threadIdx.x;
    const int w    = tid >> 6;         // wave 0..7
    const int l    = tid & 63;
    const int l15  = l & 15;
    const int lg   = l >> 4;           // 0..3
    const int hgrp = w >> 2;           // head pair 0/1
    const int m_w  = w & 3;            // query row tile

    const int blk = blockIdx.x;
    const int b   = blk >> 8;
    const int wi  = blk & 255;
    const int hs0 = (wi >> 4) * 7;
    const int ws0 = (wi & 15) * 7;

    const float* xb = x + (size_t)b * (IMGH * IMGW * 128);

    // ---- stage 0: metadata + rpb + x -> LDS ----
    if (tid < 64) {
        int rowc = tid < NWIN ? tid : NWIN - 1;
        int ri = (rowc * 9363) >> 16;
        int ci = rowc - ri * 7;
        int hc = hs0 + ri, wc = ws0 + ci;
        int reg = (hc < 105 ? 0 : (hc < 109 ? 1 : 2)) * 3
                + (wc < 105 ? 0 : (wc < 109 ? 1 : 2));
        if (tid >= NWIN) reg = 255;
        s_meta[tid] = (ri * 13 + ci) | (reg << 8);
        int gh = hc + SHIFT; if (gh >= IMGH) gh -= IMGH;
        int gw = wc + SHIFT; if (gw >= IMGW) gw -= IMGW;
        s_gout[tid] = gh * IMGW + gw;
    }
    if (tid < 338) {
        int hg  = tid < 169 ? 0 : 1;
        int idx = tid - hg * 169;
        float2 v = *(const float2*)(rpb + idx * 4 + hg * 2);
        v.x *= LOG2E; v.y *= LOG2E;
        s_rpb[hg][idx] = v;
    }
    {
        int row  = tid >> 3;           // 0..63
        int col0 = (tid & 7) << 4;     // 0,16,...,112
        uint4 u0 = {0,0,0,0}, u1 = {0,0,0,0};
        if (row < NWIN) {
            int rr = (row * 9363) >> 16;
            int cc = row - rr * 7;
            int gh = hs0 + rr + SHIFT; if (gh >= IMGH) gh -= IMGH;
            int gw = ws0 + cc + SHIFT; if (gw >= IMGW) gw -= IMGW;
            const float* px = xb + (((size_t)(gh * IMGW + gw)) << 7) + col0;
            float4 a = *(const float4*)(px + 0);
            float4 c4 = *(const float4*)(px + 4);
            float4 e = *(const float4*)(px + 8);
            float4 g = *(const float4*)(px + 12);
            u0.x = cvtpk(a.x, a.y);   u0.y = cvtpk(a.z, a.w);
            u0.z = cvtpk(c4.x, c4.y); u0.w = cvtpk(c4.z, c4.w);
            u1.x = cvtpk(e.x, e.y);   u1.y = cvtpk(e.z, e.w);
            u1.z = cvtpk(g.x, g.y);   u1.w = cvtpk(g.z, g.w);
        }
        *(uint4*)&s_xp[row * XSTR + col0]     = u0;
        *(uint4*)&s_xp[row * XSTR + col0 + 8] = u1;
    }
    __syncthreads();

    // ---- stage 1: qkv GEMM. wave w owns n-tiles [3w, 3w+3) of 24 ----
    {
        short8 bfr[3][4];
        float  biasr[3];
        #pragma unroll
        for (int i = 0; i < 3; ++i) {
            int j0 = (w * 3 + i) << 4;
            const short* wb = wq + ((j0 + l15) << 7) + lg * 8;
            #pragma unroll
            for (int kk = 0; kk < 4; ++kk) bfr[i][kk] = *(const short8*)(wb + kk * 32);
            float bb = qkv_b[j0 + l15];
            biasr[i] = (j0 < 128) ? bb * QSCALE : bb;
        }
        for (int m = 0; m < 4; ++m) {
            short8 af[4];
            #pragma unroll
            for (int kk = 0; kk < 4; ++kk)
                af[kk] = *(const short8*)&s_xp[(m * 16 + l15) * XSTR + kk * 32 + lg * 8];
            floatx4 acc[3];
            #pragma unroll
            for (int i = 0; i < 3; ++i) acc[i] = zero4();
            #pragma unroll
            for (int kk = 0; kk < 4; ++kk)
                #pragma unroll
                for (int i = 0; i < 3; ++i)
                    acc[i] = mfma16(af[kk], bfr[i][kk], acc[i]);
            #pragma unroll
            for (int i = 0; i < 3; ++i) {
                int j0 = (w * 3 + i) << 4;
                #pragma unroll
                for (int c = 0; c < 4; ++c) {
                    int row = m * 16 + lg * 4 + c;
                    unsigned short v = f2bf1(acc[i][c] + biasr[i]);
                    if (j0 < 256) s_qk[row * QKSTR + j0 + l15] = (short)v;
                    else          s_vt[(j0 - 256 + l15) * VTSTR + row] = (short)v;
                }
            }
        }
    }
    __syncthreads();   // x consumed; s_xp becomes P/O storage

    // ---- bias+mask for both heads of this wave's pair, computed once ----
    float2 b2[4][4];   // [c][n]
    {
        int mj[4];
        #pragma unroll
        for (int n = 0; n < 4; ++n) mj[n] = s_meta[n * 16 + l15];
        #pragma unroll
        for (int c = 0; c < 4; ++c) {
            int mi = s_meta[m_w * 16 + lg * 4 + c];
            int ti = mi & 255, gi = mi >> 8;
            #pragma unroll
            for (int n = 0; n < 4; ++n) {
                int d = ti - (mj[n] & 255) + 84;
                float msk = (gi == (mj[n] >> 8)) ? 0.f : NMASK;
                float2 r2 = s_rpb[hgrp][d];
                b2[c][n].x = r2.x + msk;
                b2[c][n].y = r2.y + msk;
            }
        }
    }

    // ---- stage 2: two heads per wave; P slot keyed on hgrp (race-free),
    //      reused serially across hh (intra-wave LDS ordering) ----
    floatx4 accO[2][2];    // [hh][vt]
    float   inv[2][4];     // [hh][c]
    #pragma unroll
    for (int hh = 0; hh < 2; ++hh) {
        const int h = hgrp * 2 + hh;
        short8 qf = *(const short8*)&s_qk[(m_w * 16 + l15) * QKSTR + h * 32 + lg * 8];
        floatx4 accS[4];
        #pragma unroll
        for (int n = 0; n < 4; ++n) {
            short8 kf = *(const short8*)&s_qk[(n * 16 + l15) * QKSTR + 128 + h * 32 + lg * 8];
            accS[n] = mfma16(qf, kf, zero4());
        }
        float p[4][4];     // [n][c]
        #pragma unroll
        for (int n = 0; n < 4; ++n)
            #pragma unroll
            for (int c = 0; c < 4; ++c)
                p[n][c] = accS[n][c] + (hh ? b2[c][n].y : b2[c][n].x);
        // softmax (exp2 domain), normalization deferred to O-write
        #pragma unroll
        for (int c = 0; c < 4; ++c) {
            float mx = fmaxf(fmaxf(p[0][c], p[1][c]), fmaxf(p[2][c], p[3][c]));
            #pragma unroll
            for (int msk = 1; msk <= 8; msk <<= 1) mx = fmaxf(mx, __shfl_xor(mx, msk, 64));
            float sm = 0.f;
            #pragma unroll
            for (int n = 0; n < 4; ++n) { p[n][c] = exp2f(p[n][c] - mx); sm += p[n][c]; }
            #pragma unroll
            for (int msk = 1; msk <= 8; msk <<= 1) sm += __shfl_xor(sm, msk, 64);
            inv[hh][c] = 1.f / sm;
        }
        // P -> s_xp slot (cols hgrp*72.., rows m_w*16.. : wave-private)
        #pragma unroll
        for (int n = 0; n < 4; ++n)
            #pragma unroll
            for (int c = 0; c < 4; ++c)
                s_xp[(m_w * 16 + lg * 4 + c) * XSTR + hgrp * 72 + n * 16 + l15] =
                    (short)f2bf1(p[n][c]);
        short8 pa[2];
        #pragma unroll
        for (int kt = 0; kt < 2; ++kt)
            pa[kt] = *(const short8*)&s_xp[(m_w * 16 + l15) * XSTR + hgrp * 72 + kt * 32 + lg * 8];
        #pragma unroll
        for (int vt = 0; vt < 2; ++vt) accO[hh][vt] = zero4();
        #pragma unroll
        for (int kt = 0; kt < 2; ++kt)
            #pragma unroll
            for (int vt = 0; vt < 2; ++vt) {
                short8 vf = *(const short8*)&s_vt[(h * 32 + vt * 16 + l15) * VTSTR + kt * 32 + lg * 8];
                accO[hh][vt] = mfma16(pa[kt], vf, accO[hh][vt]);
            }
    }
    __syncthreads();   // all P consumed before O overwrites s_xp

    // ---- O (normalized) -> s_xp cols hgrp*64+hh*32+vt*16+l15 ----
    #pragma unroll
    for (int hh = 0; hh < 2; ++hh)
        #pragma unroll
        for (int vt = 0; vt < 2; ++vt)
            #pragma unroll
            for (int c = 0; c < 4; ++c)
                s_xp[(m_w * 16 + lg * 4 + c) * XSTR + hgrp * 64 + hh * 32 + vt * 16 + l15] =
                    (short)f2bf1(accO[hh][vt][c] * inv[hh][c]);
    __syncthreads();

    // ---- stage 3: proj + scatter via s_gout ----
    {
        floatx4 acc[4];
        #pragma unroll
        for (int m = 0; m < 4; ++m) acc[m] = zero4();
        const short* wbp = wp + ((w * 16 + l15) << 7) + lg * 8;
        #pragma unroll
        for (int kk = 0; kk < 4; ++kk) {
            short8 bfr = *(const short8*)(wbp + kk * 32);
            #pragma unroll
            for (int m = 0; m < 4; ++m) {
                short8 of = *(const short8*)&s_xp[(m * 16 + l15) * XSTR + kk * 32 + lg * 8];
                acc[m] = mfma16(of, bfr, acc[m]);
            }
        }
        float bias = proj_b[w * 16 + l15];
        const size_t obase = (size_t)b * (IMGH * IMGW);
        #pragma unroll
        for (int m = 0; m < 4; ++m)
            #pragma unroll
            for (int c = 0; c < 4; ++c) {
                int row = m * 16 + lg * 4 + c;
                if (row < NWIN)
                    out[((obase + s_gout[row]) << 7) + w * 16 + l15] = acc[m][c] + bias;
            }
    }
}

extern "C" void kernel_launch(void* const* d_in, const int* in_sizes, int n_in,
                              void* d_out, int out_size, void* d_ws, size_t ws_size,
                              hipStream_t stream) {
    const float* x      = (const float*)d_in[0];
    const float* qkv_w  = (const float*)d_in[1];
    const float* qkv_b  = (const float*)d_in[2];
    const float* proj_w = (const float*)d_in[3];
    const float* proj_b = (const float*)d_in[4];
    const float* rpb    = (const float*)d_in[5];
    float* out = (float*)d_out;
    short* wbf = (short*)d_ws;   // [0,49152) qkv_w bf16 (Q rows pre-scaled), [49152,65536) proj_w

    hipLaunchKernelGGL(convert_w, dim3(192), dim3(256), 0, stream, qkv_w, proj_w, wbf);
    hipLaunchKernelGGL(win_attn_mfma8, dim3(4096), dim3(512), 0, stream,
                       x, qkv_b, proj_b, rpb, wbf, wbf + 49152, out);
}

// Round 14
// 109.535 us; speedup vs baseline: 51.4406x; 1.1051x over previous
//
#include <hip/hip_runtime.h>
#include <hip/hip_bf16.h>

typedef __attribute__((ext_vector_type(8))) short short8;
typedef __attribute__((ext_vector_type(4))) float floatx4;

#define IMGH 112
#define IMGW 112
#define SHIFT 3
#define NWIN 49

#define XSTR 152     // s_xp row stride (x / P / O)
#define QKSTR 280    // s_qk row stride (Q 0-127, K 128-255)
#define VTSTR 88     // s_vt row stride (V^T)

#define LOG2E 1.4426950408889634f
#define QSCALE (0.17677669529663687f * LOG2E)
#define NMASK (-100.0f * LOG2E)

__device__ inline unsigned short f2bf1(float f) {
    unsigned r;
    asm("v_cvt_pk_bf16_f32 %0, %1, %1" : "=v"(r) : "v"(f));
    return (unsigned short)r;
}
__device__ inline unsigned cvtpk(float lo, float hi) {
    unsigned r;
    asm("v_cvt_pk_bf16_f32 %0, %1, %2" : "=v"(r) : "v"(lo), "v"(hi));
    return r;
}

__device__ inline floatx4 mfma16(short8 a, short8 b, floatx4 c) {
    return __builtin_amdgcn_mfma_f32_16x16x32_bf16(a, b, c, 0, 0, 0);
}
__device__ inline floatx4 zero4() {
    floatx4 z; z[0] = 0.f; z[1] = 0.f; z[2] = 0.f; z[3] = 0.f; return z;
}
__device__ inline short8 ones8() {          // bf16 1.0 in all 8 slots
    short8 z;
    #pragma unroll
    for (int i = 0; i < 8; ++i) z[i] = (short)0x3F80;
    return z;
}

// weight fp32 -> bf16 (Q rows pre-scaled by scale*log2e)
__global__ __launch_bounds__(256) void convert_w(const float* __restrict__ qkv_w,
                                                 const float* __restrict__ proj_w,
                                                 short* __restrict__ ws) {
    int i = blockIdx.x * 256 + threadIdx.x;
    if (i < 49152) {
        float v = qkv_w[i];
        if (i < 16384) v *= QSCALE;          // rows 0..127 = Q features
        ws[i] = (short)f2bf1(v);
    }
    if (i < 16384) ws[49152 + i] = (short)f2bf1(proj_w[i]);
}

// One block per 7x7 window, 8 waves. r13 base; softmax reductions replaced by
// no-max exp2 + MFMA row-sum (ones-operand trick) -> zero shuffles in stage 2.
__global__ __launch_bounds__(512, 4) void win_attn_mfma8(
    const float* __restrict__ x,
    const float* __restrict__ qkv_b,
    const float* __restrict__ proj_b,
    const float* __restrict__ rpb,
    const short* __restrict__ wq,    // bf16 qkv_w [384][128] (Q rows scaled)
    const short* __restrict__ wp,    // bf16 proj_w [128][128]
    float* __restrict__ out)
{
    __shared__ alignas(16) short s_xp[64 * XSTR];    // x -> P slots -> O
    __shared__ alignas(16) short s_qk[64 * QKSTR];
    __shared__ alignas(16) short s_vt[128 * VTSTR];
    __shared__ float2 s_rpb[2][169];                 // pre-scaled by LOG2E
    __shared__ int s_meta[64];                       // t13 | reg<<8
    __shared__ int s_gout[64];                       // scatter pixel index

    const int tid = threadIdx.x;
    const int w    = tid >> 6;         // wave 0..7
    const int l    = tid & 63;
    const int l15  = l & 15;
    const int lg   = l >> 4;           // 0..3
    const int hgrp = w >> 2;           // head pair 0/1
    const int m_w  = w & 3;            // query row tile

    const int blk = blockIdx.x;
    const int b   = blk >> 8;
    const int wi  = blk & 255;
    const int hs0 = (wi >> 4) * 7;
    const int ws0 = (wi & 15) * 7;

    const float* xb = x + (size_t)b * (IMGH * IMGW * 128);

    // ---- stage 0: metadata + rpb + x -> LDS ----
    if (tid < 64) {
        int rowc = tid < NWIN ? tid : NWIN - 1;
        int ri = (rowc * 9363) >> 16;
        int ci = rowc - ri * 7;
        int hc = hs0 + ri, wc = ws0 + ci;
        int reg = (hc < 105 ? 0 : (hc < 109 ? 1 : 2)) * 3
                + (wc < 105 ? 0 : (wc < 109 ? 1 : 2));
        if (tid >= NWIN) reg = 255;
        s_meta[tid] = (ri * 13 + ci) | (reg << 8);
        int gh = hc + SHIFT; if (gh >= IMGH) gh -= IMGH;
        int gw = wc + SHIFT; if (gw >= IMGW) gw -= IMGW;
        s_gout[tid] = gh * IMGW + gw;
    }
    if (tid < 338) {
        int hg  = tid < 169 ? 0 : 1;
        int idx = tid - hg * 169;
        float2 v = *(const float2*)(rpb + idx * 4 + hg * 2);
        v.x *= LOG2E; v.y *= LOG2E;
        s_rpb[hg][idx] = v;
    }
    {
        int row  = tid >> 3;           // 0..63
        int col0 = (tid & 7) << 4;     // 0,16,...,112
        uint4 u0 = {0,0,0,0}, u1 = {0,0,0,0};
        if (row < NWIN) {
            int rr = (row * 9363) >> 16;
            int cc = row - rr * 7;
            int gh = hs0 + rr + SHIFT; if (gh >= IMGH) gh -= IMGH;
            int gw = ws0 + cc + SHIFT; if (gw >= IMGW) gw -= IMGW;
            const float* px = xb + (((size_t)(gh * IMGW + gw)) << 7) + col0;
            float4 a = *(const float4*)(px + 0);
            float4 c4 = *(const float4*)(px + 4);
            float4 e = *(const float4*)(px + 8);
            float4 g = *(const float4*)(px + 12);
            u0.x = cvtpk(a.x, a.y);   u0.y = cvtpk(a.z, a.w);
            u0.z = cvtpk(c4.x, c4.y); u0.w = cvtpk(c4.z, c4.w);
            u1.x = cvtpk(e.x, e.y);   u1.y = cvtpk(e.z, e.w);
            u1.z = cvtpk(g.x, g.y);   u1.w = cvtpk(g.z, g.w);
        }
        *(uint4*)&s_xp[row * XSTR + col0]     = u0;
        *(uint4*)&s_xp[row * XSTR + col0 + 8] = u1;
    }
    __syncthreads();

    // ---- stage 1: qkv GEMM. wave w owns n-tiles [3w, 3w+3) of 24 ----
    {
        short8 bfr[3][4];
        float  biasr[3];
        #pragma unroll
        for (int i = 0; i < 3; ++i) {
            int j0 = (w * 3 + i) << 4;
            const short* wb = wq + ((j0 + l15) << 7) + lg * 8;
            #pragma unroll
            for (int kk = 0; kk < 4; ++kk) bfr[i][kk] = *(const short8*)(wb + kk * 32);
            float bb = qkv_b[j0 + l15];
            biasr[i] = (j0 < 128) ? bb * QSCALE : bb;
        }
        for (int m = 0; m < 4; ++m) {
            short8 af[4];
            #pragma unroll
            for (int kk = 0; kk < 4; ++kk)
                af[kk] = *(const short8*)&s_xp[(m * 16 + l15) * XSTR + kk * 32 + lg * 8];
            floatx4 acc[3];
            #pragma unroll
            for (int i = 0; i < 3; ++i) acc[i] = zero4();
            #pragma unroll
            for (int kk = 0; kk < 4; ++kk)
                #pragma unroll
                for (int i = 0; i < 3; ++i)
                    acc[i] = mfma16(af[kk], bfr[i][kk], acc[i]);
            #pragma unroll
            for (int i = 0; i < 3; ++i) {
                int j0 = (w * 3 + i) << 4;
                #pragma unroll
                for (int c = 0; c < 4; ++c) {
                    int row = m * 16 + lg * 4 + c;
                    unsigned short v = f2bf1(acc[i][c] + biasr[i]);
                    if (j0 < 256) s_qk[row * QKSTR + j0 + l15] = (short)v;
                    else          s_vt[(j0 - 256 + l15) * VTSTR + row] = (short)v;
                }
            }
        }
    }
    __syncthreads();   // x consumed; s_xp becomes P/O storage

    // ---- bias+mask for both heads of this wave's pair, computed once ----
    float2 b2[4][4];   // [c][n]
    {
        int mj[4];
        #pragma unroll
        for (int n = 0; n < 4; ++n) mj[n] = s_meta[n * 16 + l15];
        #pragma unroll
        for (int c = 0; c < 4; ++c) {
            int mi = s_meta[m_w * 16 + lg * 4 + c];
            int ti = mi & 255, gi = mi >> 8;
            #pragma unroll
            for (int n = 0; n < 4; ++n) {
                int d = ti - (mj[n] & 255) + 84;
                float msk = (gi == (mj[n] >> 8)) ? 0.f : NMASK;
                float2 r2 = s_rpb[hgrp][d];
                b2[c][n].x = r2.x + msk;
                b2[c][n].y = r2.y + msk;
            }
        }
    }

    // ---- stage 2: two heads per wave; no-max exp2 softmax, MFMA row-sum ----
    floatx4 accO[2][2];    // [hh][vt]
    float   inv[2][4];     // [hh][c]
    const short8 vone = ones8();
    #pragma unroll
    for (int hh = 0; hh < 2; ++hh) {
        const int h = hgrp * 2 + hh;
        short8 qf = *(const short8*)&s_qk[(m_w * 16 + l15) * QKSTR + h * 32 + lg * 8];
        floatx4 accS[4];
        #pragma unroll
        for (int n = 0; n < 4; ++n) {
            short8 kf = *(const short8*)&s_qk[(n * 16 + l15) * QKSTR + 128 + h * 32 + lg * 8];
            accS[n] = mfma16(qf, kf, zero4());
        }
        // logits are bounded (|S|<~5; masked/-pad keys get -144 -> exp2 -> 0),
        // so no max-subtraction needed: exp2 directly.
        float p[4][4];     // [n][c]
        #pragma unroll
        for (int n = 0; n < 4; ++n)
            #pragma unroll
            for (int c = 0; c < 4; ++c)
                p[n][c] = exp2f(accS[n][c] + (hh ? b2[c][n].y : b2[c][n].x));
        // P -> s_xp slot (cols hgrp*72.., rows m_w*16.. : wave-private)
        #pragma unroll
        for (int n = 0; n < 4; ++n)
            #pragma unroll
            for (int c = 0; c < 4; ++c)
                s_xp[(m_w * 16 + lg * 4 + c) * XSTR + hgrp * 72 + n * 16 + l15] =
                    (short)f2bf1(p[n][c]);
        short8 pa[2];
        #pragma unroll
        for (int kt = 0; kt < 2; ++kt)
            pa[kt] = *(const short8*)&s_xp[(m_w * 16 + l15) * XSTR + hgrp * 72 + kt * 32 + lg * 8];
        // PV + row-sum via all-ones B operand: D[r][c] = rowsum[r] for every c,
        // so each lane's reg c holds the sum for its own row lg*4+c.
        floatx4 accSum = zero4();
        #pragma unroll
        for (int vt = 0; vt < 2; ++vt) accO[hh][vt] = zero4();
        #pragma unroll
        for (int kt = 0; kt < 2; ++kt) {
            #pragma unroll
            for (int vt = 0; vt < 2; ++vt) {
                short8 vf = *(const short8*)&s_vt[(h * 32 + vt * 16 + l15) * VTSTR + kt * 32 + lg * 8];
                accO[hh][vt] = mfma16(pa[kt], vf, accO[hh][vt]);
            }
            accSum = mfma16(pa[kt], vone, accSum);
        }
        #pragma unroll
        for (int c = 0; c < 4; ++c) inv[hh][c] = 1.f / accSum[c];
    }
    __syncthreads();   // all P consumed before O overwrites s_xp

    // ---- O (normalized) -> s_xp cols hgrp*64+hh*32+vt*16+l15 ----
    #pragma unroll
    for (int hh = 0; hh < 2; ++hh)
        #pragma unroll
        for (int vt = 0; vt < 2; ++vt)
            #pragma unroll
            for (int c = 0; c < 4; ++c)
                s_xp[(m_w * 16 + lg * 4 + c) * XSTR + hgrp * 64 + hh * 32 + vt * 16 + l15] =
                    (short)f2bf1(accO[hh][vt][c] * inv[hh][c]);
    __syncthreads();

    // ---- stage 3: proj + scatter via s_gout ----
    {
        floatx4 acc[4];
        #pragma unroll
        for (int m = 0; m < 4; ++m) acc[m] = zero4();
        const short* wbp = wp + ((w * 16 + l15) << 7) + lg * 8;
        #pragma unroll
        for (int kk = 0; kk < 4; ++kk) {
            short8 bfr = *(const short8*)(wbp + kk * 32);
            #pragma unroll
            for (int m = 0; m < 4; ++m) {
                short8 of = *(const short8*)&s_xp[(m * 16 + l15) * XSTR + kk * 32 + lg * 8];
                acc[m] = mfma16(of, bfr, acc[m]);
            }
        }
        float bias = proj_b[w * 16 + l15];
        const size_t obase = (size_t)b * (IMGH * IMGW);
        #pragma unroll
        for (int m = 0; m < 4; ++m)
            #pragma unroll
            for (int c = 0; c < 4; ++c) {
                int row = m * 16 + lg * 4 + c;
                if (row < NWIN)
                    out[((obase + s_gout[row]) << 7) + w * 16 + l15] = acc[m][c] + bias;
            }
    }
}

extern "C" void kernel_launch(void* const* d_in, const int* in_sizes, int n_in,
                              void* d_out, int out_size, void* d_ws, size_t ws_size,
                              hipStream_t stream) {
    const float* x      = (const float*)d_in[0];
    const float* qkv_w  = (const float*)d_in[1];
    const float* qkv_b  = (const float*)d_in[2];
    const float* proj_w = (const float*)d_in[3];
    const float* proj_b = (const float*)d_in[4];
    const float* rpb    = (const float*)d_in[5];
    float* out = (float*)d_out;
    short* wbf = (short*)d_ws;   // [0,49152) qkv_w bf16 (Q rows pre-scaled), [49152,65536) proj_w

    hipLaunchKernelGGL(convert_w, dim3(192), dim3(256), 0, stream, qkv_w, proj_w, wbf);
    hipLaunchKernelGGL(win_attn_mfma8, dim3(4096), dim3(512), 0, stream,
                       x, qkv_b, proj_b, rpb, wbf, wbf + 49152, out);
}